// Round 6
// baseline (256.977 us; speedup 1.0000x reference)
//
#include <hip/hip_runtime.h>
#include <hip/hip_bf16.h>
#include <math.h>

// out = tanh(x * sigmoid(x)) + sigmoid(x), elementwise fp32, N = 16*2048*4096.
// Memory-bound: 1.073 GB traffic -> ~170 us floor at 6.3 TB/s copy ceiling.
// R5 post-mortem: nontemporal was NOT the cause of 244 vs 211; this round is
// R1's EXACT loop/launch structure (guarded grid-stride, HIP float4, unroll 4)
// with ONLY act() swapped to fast exp2/rcp. Isolates loop-form vs act().

#define LOG2E 1.44269504088896341f

__device__ __forceinline__ float fast_rcp(float a) {
    return __builtin_amdgcn_rcpf(a);   // v_rcp_f32, ~1 ulp
}

__device__ __forceinline__ float fast_exp(float a) {
    return __builtin_amdgcn_exp2f(a * LOG2E);  // v_exp_f32 computes 2^x
}

__device__ __forceinline__ float act(float v) {
    float s = fast_rcp(1.0f + fast_exp(-v));      // sigmoid(x)
    float z = v * s;                               // silu(x)
    float t = 1.0f - 2.0f * fast_rcp(fast_exp(2.0f * z) + 1.0f);  // tanh(z)
    return t + s;
}

__global__ void __launch_bounds__(256)
dynact_kernel(const float* __restrict__ x, float* __restrict__ out, long long n4) {
    const long long stride = (long long)gridDim.x * blockDim.x;
    const float4* __restrict__ x4 = (const float4*)x;
    float4* __restrict__ o4 = (float4*)out;
    #pragma unroll 4
    for (long long i = (long long)blockIdx.x * blockDim.x + threadIdx.x; i < n4; i += stride) {
        float4 v = x4[i];
        float4 r;
        r.x = act(v.x);
        r.y = act(v.y);
        r.z = act(v.z);
        r.w = act(v.w);
        o4[i] = r;
    }
}

// Scalar tail if n % 4 != 0 (not the case here: 16*2048*4096 % 4 == 0).
__global__ void dynact_tail(const float* __restrict__ x, float* __restrict__ out,
                            long long start, long long n) {
    long long i = start + (long long)blockIdx.x * blockDim.x + threadIdx.x;
    if (i < n) out[i] = act(x[i]);
}

extern "C" void kernel_launch(void* const* d_in, const int* in_sizes, int n_in,
                              void* d_out, int out_size, void* d_ws, size_t ws_size,
                              hipStream_t stream) {
    const float* x = (const float*)d_in[0];
    float* out = (float*)d_out;
    long long n = (long long)in_sizes[0];
    long long n4 = n >> 2;

    const int block = 256;
    int grid = (int)((n4 + block - 1) / block);
    if (grid > 2048) grid = 2048;
    if (grid > 0) {
        dynact_kernel<<<grid, block, 0, stream>>>(x, out, n4);
    }

    long long rem_start = n4 << 2;
    long long rem = n - rem_start;
    if (rem > 0) {
        int tgrid = (int)((rem + block - 1) / block);
        dynact_tail<<<tgrid, block, 0, stream>>>(x, out, rem_start, n);
    }
}

// Round 7
// 211.175 us; speedup vs baseline: 1.2169x; 1.2169x over previous
//
#include <hip/hip_runtime.h>
#include <hip/hip_bf16.h>
#include <math.h>

// out = tanh(x * sigmoid(x)) + sigmoid(x), elementwise fp32.
// Memory-bound: 1.07 GB traffic -> target ~6.3 TB/s -> ~170 us.
// R7 = byte-exact resubmission of R1's 211 us kernel to measure cross-run noise.

__global__ void __launch_bounds__(256)
dynact_kernel(const float* __restrict__ x, float* __restrict__ out, long long n4) {
    const long long stride = (long long)gridDim.x * blockDim.x;
    const float4* __restrict__ x4 = (const float4*)x;
    float4* __restrict__ o4 = (float4*)out;
    for (long long i = (long long)blockIdx.x * blockDim.x + threadIdx.x; i < n4; i += stride) {
        float4 v = x4[i];
        float4 r;
        {
            float s = 1.0f / (1.0f + __expf(-v.x));
            r.x = tanhf(v.x * s) + s;
        }
        {
            float s = 1.0f / (1.0f + __expf(-v.y));
            r.y = tanhf(v.y * s) + s;
        }
        {
            float s = 1.0f / (1.0f + __expf(-v.z));
            r.z = tanhf(v.z * s) + s;
        }
        {
            float s = 1.0f / (1.0f + __expf(-v.w));
            r.w = tanhf(v.w * s) + s;
        }
        o4[i] = r;
    }
}

// Tail kernel for safety if n % 4 != 0 (not the case here: 16*2048*4096 % 4 == 0).
__global__ void dynact_tail(const float* __restrict__ x, float* __restrict__ out,
                            long long start, long long n) {
    long long i = start + blockIdx.x * blockDim.x + threadIdx.x;
    if (i < n) {
        float v = x[i];
        float s = 1.0f / (1.0f + __expf(-v));
        out[i] = tanhf(v * s) + s;
    }
}

extern "C" void kernel_launch(void* const* d_in, const int* in_sizes, int n_in,
                              void* d_out, int out_size, void* d_ws, size_t ws_size,
                              hipStream_t stream) {
    const float* x = (const float*)d_in[0];
    float* out = (float*)d_out;
    long long n = (long long)in_sizes[0];
    long long n4 = n >> 2;

    const int block = 256;
    int grid = (int)((n4 + block - 1) / block);
    if (grid > 2048) grid = 2048;
    if (grid > 0) {
        dynact_kernel<<<grid, block, 0, stream>>>(x, out, n4);
    }

    long long rem_start = n4 << 2;
    long long rem = n - rem_start;
    if (rem > 0) {
        int tgrid = (int)((rem + block - 1) / block);
        dynact_tail<<<tgrid, block, 0, stream>>>(x, out, rem_start, n);
    }
}

// Round 8
// 209.791 us; speedup vs baseline: 1.2249x; 1.0066x over previous
//
#include <hip/hip_runtime.h>
#include <hip/hip_bf16.h>
#include <math.h>

// out = tanh(x * sigmoid(x)) + sigmoid(x), elementwise fp32.
// Memory-bound: 1.07 GB traffic -> ~170 us floor at 6.3 TB/s.
// R8 = R1's exact loop/launch structure (guarded grid-stride, NO unroll pragma,
// HIP float4) with ONLY act() swapped to fast exp2/rcp. Isolates act() from
// loop restructuring (the entangled variable in the R4-R6 regressions).

#define LOG2E 1.44269504088896341f

__device__ __forceinline__ float fast_rcp(float a) {
    return __builtin_amdgcn_rcpf(a);   // v_rcp_f32, ~1 ulp
}

__device__ __forceinline__ float fast_exp(float a) {
    return __builtin_amdgcn_exp2f(a * LOG2E);  // v_exp_f32 computes 2^x
}

__device__ __forceinline__ float act(float v) {
    float s = fast_rcp(1.0f + fast_exp(-v));      // sigmoid(x)
    float z = v * s;                               // silu(x)
    float t = 1.0f - 2.0f * fast_rcp(fast_exp(2.0f * z) + 1.0f);  // tanh(z)
    return t + s;
}

__global__ void __launch_bounds__(256)
dynact_kernel(const float* __restrict__ x, float* __restrict__ out, long long n4) {
    const long long stride = (long long)gridDim.x * blockDim.x;
    const float4* __restrict__ x4 = (const float4*)x;
    float4* __restrict__ o4 = (float4*)out;
    for (long long i = (long long)blockIdx.x * blockDim.x + threadIdx.x; i < n4; i += stride) {
        float4 v = x4[i];
        float4 r;
        r.x = act(v.x);
        r.y = act(v.y);
        r.z = act(v.z);
        r.w = act(v.w);
        o4[i] = r;
    }
}

// Tail kernel for safety if n % 4 != 0 (not the case here: 16*2048*4096 % 4 == 0).
__global__ void dynact_tail(const float* __restrict__ x, float* __restrict__ out,
                            long long start, long long n) {
    long long i = start + blockIdx.x * blockDim.x + threadIdx.x;
    if (i < n) {
        out[i] = act(x[i]);
    }
}

extern "C" void kernel_launch(void* const* d_in, const int* in_sizes, int n_in,
                              void* d_out, int out_size, void* d_ws, size_t ws_size,
                              hipStream_t stream) {
    const float* x = (const float*)d_in[0];
    float* out = (float*)d_out;
    long long n = (long long)in_sizes[0];
    long long n4 = n >> 2;

    const int block = 256;
    int grid = (int)((n4 + block - 1) / block);
    if (grid > 2048) grid = 2048;
    if (grid > 0) {
        dynact_kernel<<<grid, block, 0, stream>>>(x, out, n4);
    }

    long long rem_start = n4 << 2;
    long long rem = n - rem_start;
    if (rem > 0) {
        int tgrid = (int)((rem + block - 1) / block);
        dynact_tail<<<tgrid, block, 0, stream>>>(x, out, rem_start, n);
    }
}